// Round 7
// baseline (1360.629 us; speedup 1.0000x reference)
//
#include <hip/hip_runtime.h>
#include <math.h>

// ---------------- wavelet filter constants (orthogonal, L=12) ----------------
#define W0f  (-0.00107730108499558f)
#define W1f  (0.004777257511010651f)
#define W2f  (0.0005538422009938016f)
#define W3f  (-0.031582039318031156f)
#define W4f  (0.02752286553001629f)
#define W5f  (0.09750160558707936f)
#define W6f  (-0.12976686756709563f)
#define W7f  (-0.22626469396516913f)
#define W8f  (0.3152503517092432f)
#define W9f  (0.7511339080215775f)
#define W10f (0.4946238903983854f)
#define W11f (0.11154074335008017f)

__constant__ float cKA0[12] = {W11f,W10f,W9f,W8f,W7f,W6f,W5f,W4f,W3f,W2f,W1f,W0f};
__constant__ float cKA1[12] = {W0f,-W1f,W2f,-W3f,W4f,-W5f,W6f,-W7f,W8f,-W9f,W10f,-W11f};
__constant__ float cKS0[12] = {W0f,W1f,W2f,W3f,W4f,W5f,W6f,W7f,W8f,W9f,W10f,W11f};
__constant__ float cKS1[12] = {-W11f,W10f,-W9f,W8f,-W7f,W6f,-W5f,W4f,-W3f,W2f,-W1f,W0f};

// problem-size constants
#define S1c 134
#define S2c 72
#define S3c 41
#define A3c 1681
#define N1c 4596736UL   // 256*134*134
#define N2c 1327104UL   // 256*72*72
#define N3c 430336UL    // 256*41*41
#define PLc 2480128UL   // per-layer interp'd weights

// fast erf (Abramowitz-Stegun 7.1.26, max abs err 1.5e-7)
__device__ __forceinline__ float gelu_f(float x) {
    float z  = x * 0.70710678118654752440f;
    float az = fabsf(z);
    float t  = __builtin_amdgcn_rcpf(1.0f + 0.3275911f * az);
    float p  = t * (0.254829592f + t * (-0.284496736f + t * (1.421413741f +
               t * (-1.453152027f + t * 1.061405429f))));
    float e  = __expf(-az * az);
    float er = copysignf(1.0f - p * e, z);
    return 0.5f * x * (1.0f + er);
}

// ---------------- fused 2D analysis DWT (one level, generic) ----------------
__global__ __launch_bounds__(256) void dwt2d(
    const float* __restrict__ in, float* __restrict__ ll, float* __restrict__ lh,
    float* __restrict__ hl, float* __restrict__ hh, int H, int W, int Ho, int Wo) {
    int c   = blockIdx.z;
    int ty0 = blockIdx.y * 16;
    int tx0 = blockIdx.x * 16;
    const float* img = in + (size_t)c * H * W;
    __shared__ float sIn[42][44];
    __shared__ float rlo[42][17];
    __shared__ float rhi[42][17];
    int tid = threadIdx.x;
    for (int idx = tid; idx < 42 * 42; idx += 256) {
        int r = idx / 42, q = idx % 42;
        int gy = 2 * ty0 - 10 + r;
        int gx = 2 * tx0 - 10 + q;
        gy = gy < 0 ? -1 - gy : (gy >= H ? 2 * H - 1 - gy : gy);
        gx = gx < 0 ? -1 - gx : (gx >= W ? 2 * W - 1 - gx : gx);
        sIn[r][q] = img[gy * W + gx];
    }
    __syncthreads();
    for (int idx = tid; idx < 42 * 16; idx += 256) {
        int r = idx / 16, j = idx % 16;
        float alo = 0.f, ahi = 0.f;
        #pragma unroll
        for (int t = 0; t < 12; t++) {
            float v = sIn[r][2 * j + t];
            alo += v * cKA0[t];
            ahi += v * cKA1[t];
        }
        rlo[r][j] = alo; rhi[r][j] = ahi;
    }
    __syncthreads();
    int jy = tid / 16, jx = tid % 16;
    int oy = ty0 + jy, ox = tx0 + jx;
    if (oy < Ho && ox < Wo) {
        float a0 = 0.f, a1 = 0.f, a2 = 0.f, a3 = 0.f;
        #pragma unroll
        for (int t = 0; t < 12; t++) {
            float vl = rlo[2 * jy + t][jx];
            float vh = rhi[2 * jy + t][jx];
            a0 += vl * cKA0[t]; a1 += vl * cKA1[t];
            a2 += vh * cKA0[t]; a3 += vh * cKA1[t];
        }
        size_t o = (size_t)c * Ho * Wo + (size_t)oy * Wo + ox;
        ll[o] = a0; lh[o] = a1; hl[o] = a2; hh[o] = a3;
    }
}

// ---------------- layer-0 DWT L1 with fc0 + reflect-pad fused in ----------------
__global__ __launch_bounds__(256) void dwt2d_fc0(
    const float* __restrict__ u, const float* __restrict__ par,
    const float* __restrict__ xg, const float* __restrict__ yg,
    const float* __restrict__ fw, const float* __restrict__ fb,
    float* __restrict__ ll, float* __restrict__ lh,
    float* __restrict__ hl, float* __restrict__ hh) {
    const int Hd = 258, S = 256, Ho = S1c, Wo = S1c;
    int c   = blockIdx.z;
    int b   = c >> 5, o = c & 31;
    float w0 = fw[o*4], w1 = fw[o*4+1], w2 = fw[o*4+2], w3 = fw[o*4+3], bv = fb[o];
    int ty0 = blockIdx.y * 16;
    int tx0 = blockIdx.x * 16;
    __shared__ float sIn[42][44];
    __shared__ float rlo[42][17];
    __shared__ float rhi[42][17];
    int tid = threadIdx.x;
    for (int idx = tid; idx < 42 * 42; idx += 256) {
        int r = idx / 42, q = idx % 42;
        int gy = 2 * ty0 - 10 + r;
        int gx = 2 * tx0 - 10 + q;
        gy = gy < 0 ? -1 - gy : (gy >= Hd ? 2 * Hd - 1 - gy : gy);
        gx = gx < 0 ? -1 - gx : (gx >= Hd ? 2 * Hd - 1 - gx : gx);
        int iy = gy - 1; iy = iy < 0 ? -iy : (iy >= S ? 2 * S - 2 - iy : iy);
        int ix = gx - 1; ix = ix < 0 ? -ix : (ix >= S ? 2 * S - 2 - ix : ix);
        float vu = u  [(b * S + iy) * S + ix];
        float vp = par[(b * S + iy) * S + ix];
        sIn[r][q] = w0 * vu + w1 * vp + w2 * xg[b * S + iy] + w3 * yg[b * S + ix] + bv;
    }
    __syncthreads();
    for (int idx = tid; idx < 42 * 16; idx += 256) {
        int r = idx / 16, j = idx % 16;
        float alo = 0.f, ahi = 0.f;
        #pragma unroll
        for (int t = 0; t < 12; t++) {
            float v = sIn[r][2 * j + t];
            alo += v * cKA0[t];
            ahi += v * cKA1[t];
        }
        rlo[r][j] = alo; rhi[r][j] = ahi;
    }
    __syncthreads();
    int jy = tid / 16, jx = tid % 16;
    int oy = ty0 + jy, ox = tx0 + jx;
    if (oy < Ho && ox < Wo) {
        float a0 = 0.f, a1 = 0.f, a2 = 0.f, a3 = 0.f;
        #pragma unroll
        for (int t = 0; t < 12; t++) {
            float vl = rlo[2 * jy + t][jx];
            float vh = rhi[2 * jy + t][jx];
            a0 += vl * cKA0[t]; a1 += vl * cKA1[t];
            a2 += vh * cKA0[t]; a3 += vh * cKA1[t];
        }
        size_t oo = (size_t)c * Ho * Wo + (size_t)oy * Wo + ox;
        ll[oo] = a0; lh[oo] = a1; hl[oo] = a2; hh[oo] = a3;
    }
}

// ---------------- fused 2D synthesis IDWT (optional per-channel bias + gelu) ----------------
__global__ __launch_bounds__(256) void idwt2d(
    const float* __restrict__ ll, const float* __restrict__ lh,
    const float* __restrict__ hl, const float* __restrict__ hh,
    float* __restrict__ out, const float* __restrict__ pb,
    int h, int w, int Oh, int Ow, int do_gelu) {
    int c   = blockIdx.z;
    int my0 = blockIdx.y * 16;
    int nx0 = blockIdx.x * 16;
    __shared__ float sll[21][22], slh[21][22], shl[21][22], shh[21][22];
    __shared__ float sxl[32][22], sxh[32][22];
    int tid = threadIdx.x;
    size_t cb = (size_t)c * h * w;
    float bias = pb ? pb[c & 31] : 0.f;
    for (int idx = tid; idx < 21 * 21; idx += 256) {
        int r = idx / 21, q = idx % 21;
        int gy = min(my0 + r, h - 1);
        int gx = min(nx0 + q, w - 1);
        size_t g = cb + (size_t)gy * w + gx;
        sll[r][q] = ll[g]; slh[r][q] = lh[g];
        shl[r][q] = hl[g]; shh[r][q] = hh[g];
    }
    __syncthreads();
    for (int idx = tid; idx < 32 * 21; idx += 256) {
        int r = idx / 21, q = idx % 21;
        int mp = r >> 1, p = r & 1;
        float al = 0.f, ah = 0.f;
        #pragma unroll
        for (int s = 0; s < 6; s++) {
            float k0 = cKS0[2 * s + 1 - p];
            float k1 = cKS1[2 * s + 1 - p];
            al += sll[mp + s][q] * k0 + slh[mp + s][q] * k1;
            ah += shl[mp + s][q] * k0 + shh[mp + s][q] * k1;
        }
        sxl[r][q] = al; sxh[r][q] = ah;
    }
    __syncthreads();
    for (int idx = tid; idx < 32 * 32; idx += 256) {
        int r = idx / 32, q2 = idx % 32;
        int np = q2 >> 1, q = q2 & 1;
        int oy = 2 * my0 + r, ox = 2 * nx0 + q2;
        if (oy < Oh && ox < Ow) {
            float a = bias;
            #pragma unroll
            for (int s = 0; s < 6; s++) {
                float k0 = cKS0[2 * s + 1 - q];
                float k1 = cKS1[2 * s + 1 - q];
                a += sxl[r][np + s] * k0 + sxh[r][np + s] * k1;
            }
            if (do_gelu) a = gelu_f(a);
            out[(size_t)c * Oh * Ow + (size_t)oy * Ow + ox] = a;
        }
    }
}

// ---------------- FUSED: idwt L1 (+bias+gelu) -> dwt L1 of next layer ----------------
// Reads mixed level-1 bands of layer l; writes level-1 bands of layer l+1.
// Never materializes H. H coords always in [0,258) => band idx in [0,133]: no clamp needed.
__global__ __launch_bounds__(256) void idwt_dwt(
    const float* __restrict__ ll, const float* __restrict__ lh,
    const float* __restrict__ hl, const float* __restrict__ hh,
    float* __restrict__ oll, float* __restrict__ olh,
    float* __restrict__ ohl, float* __restrict__ ohh,
    const float* __restrict__ pb) {
    const int hb = S1c, Hd = 258, Wo = S1c;
    int c = blockIdx.z;
    int ty0 = blockIdx.y * 16, tx0 = blockIdx.x * 16;
    int ay = 2 * ty0 - 10, ax = 2 * tx0 - 10;
    float bias = pb[c & 31];
    __shared__ float sll[27][28], slh[27][28], shl[27][28], shh[27][28];
    __shared__ float sxl[42][28], sxh[42][28];
    __shared__ float sIn[42][44];
    __shared__ float rlo[42][17], rhi[42][17];
    int tid = threadIdx.x;
    // band window: min/max reflected H rows/cols -> <=27 band rows/cols
    int ylo = ay < 0 ? 0 : ay;  int yhi = ay + 41;
    if (yhi >= Hd) { ylo = min(ylo, 2 * Hd - 1 - yhi); yhi = Hd - 1; }
    int xlo = ax < 0 ? 0 : ax;  int xhi = ax + 41;
    if (xhi >= Hd) { xlo = min(xlo, 2 * Hd - 1 - xhi); xhi = Hd - 1; }
    int brow0 = ylo >> 1, bcol0 = xlo >> 1;
    size_t cb = (size_t)c * hb * hb;
    for (int idx = tid; idx < 27 * 27; idx += 256) {
        int r = idx / 27, q = idx % 27;
        int gy = min(brow0 + r, hb - 1);   // clamp only pads unused slots
        int gx = min(bcol0 + q, hb - 1);
        size_t g = cb + (size_t)gy * hb + gx;
        sll[r][q] = ll[g]; slh[r][q] = lh[g];
        shl[r][q] = hl[g]; shh[r][q] = hh[g];
    }
    __syncthreads();
    // row synthesis: 42 H rows x 27 band cols
    for (int idx = tid; idx < 42 * 27; idx += 256) {
        int yr = idx / 27, q = idx % 27;
        int t = ay + yr;
        int gy = t < 0 ? -1 - t : (t >= Hd ? 2 * Hd - 1 - t : t);
        int m = (gy >> 1) - brow0, p = gy & 1;
        float al = 0.f, ah = 0.f;
        #pragma unroll
        for (int s = 0; s < 6; s++) {
            float k0 = cKS0[2 * s + 1 - p];
            float k1 = cKS1[2 * s + 1 - p];
            al += sll[m + s][q] * k0 + slh[m + s][q] * k1;
            ah += shl[m + s][q] * k0 + shh[m + s][q] * k1;
        }
        sxl[yr][q] = al; sxh[yr][q] = ah;
    }
    __syncthreads();
    // col synthesis + bias + gelu -> H patch 42x42
    for (int idx = tid; idx < 42 * 42; idx += 256) {
        int yr = idx / 42, xr = idx % 42;
        int t = ax + xr;
        int gx = t < 0 ? -1 - t : (t >= Hd ? 2 * Hd - 1 - t : t);
        int n = (gx >> 1) - bcol0, q = gx & 1;
        float a = bias;
        #pragma unroll
        for (int s = 0; s < 6; s++) {
            float k0 = cKS0[2 * s + 1 - q];
            float k1 = cKS1[2 * s + 1 - q];
            a += sxl[yr][n + s] * k0 + sxh[yr][n + s] * k1;
        }
        sIn[yr][xr] = gelu_f(a);
    }
    __syncthreads();
    // analysis row pass
    for (int idx = tid; idx < 42 * 16; idx += 256) {
        int r = idx / 16, j = idx % 16;
        float alo = 0.f, ahi = 0.f;
        #pragma unroll
        for (int t = 0; t < 12; t++) {
            float v = sIn[r][2 * j + t];
            alo += v * cKA0[t];
            ahi += v * cKA1[t];
        }
        rlo[r][j] = alo; rhi[r][j] = ahi;
    }
    __syncthreads();
    int jy = tid / 16, jx = tid % 16;
    int oy = ty0 + jy, ox = tx0 + jx;
    if (oy < Wo && ox < Wo) {
        float a0 = 0.f, a1 = 0.f, a2 = 0.f, a3 = 0.f;
        #pragma unroll
        for (int t = 0; t < 12; t++) {
            float vl = rlo[2 * jy + t][jx];
            float vh = rhi[2 * jy + t][jx];
            a0 += vl * cKA0[t]; a1 += vl * cKA1[t];
            a2 += vh * cKA0[t]; a3 += vh * cKA1[t];
        }
        size_t o = cb + (size_t)oy * Wo + ox;
        oll[o] = a0; olh[o] = a1; ohl[o] = a2; ohh[o] = a3;
    }
}

// ---------------- transpose all 4 layers: [l][1024 io][4096 yx] -> [l][4096 yx][1024 io] ----------------
__global__ __launch_bounds__(256) void transpose_all(
    const float* __restrict__ w, float* __restrict__ wT) {
    __shared__ float t[64][65];
    int l  = blockIdx.y >> 4;
    int by = (blockIdx.y & 15) * 64; // io
    int bx = blockIdx.x * 64;        // yx
    const float* wl = w  + (size_t)l * 4194304;
    float* wTl      = wT + (size_t)l * 4194304;
    int tid = threadIdx.x;
    for (int idx = tid; idx < 4096; idx += 256) {
        int r = idx >> 6, q = idx & 63;
        t[r][q] = wl[(size_t)(by + r) * 4096 + bx + q];
    }
    __syncthreads();
    for (int idx = tid; idx < 4096; idx += 256) {
        int r = idx >> 6, q = idx & 63;
        wTl[(size_t)(bx + r) * 1024 + by + q] = t[q][r];
    }
}

// ---------------- bilinear interp of weights for all 4 layers, + pw folded in ----------------
__global__ __launch_bounds__(256) void interp4(
    const float* __restrict__ wT, const float* __restrict__ pw,
    float* __restrict__ wout) {
    int l = blockIdx.y;
    const float* wTl = wT + (size_t)l * 4194304;
    const float* pwl = pw + (size_t)l * 1024;
    float* base = wout + (size_t)l * PLc;
    __shared__ float spw[1024]; // transposed pw: spw[i*32+o] = pw[o*32+i]
    int tid = threadIdx.x;
    for (int k = tid; k < 1024; k += 256) spw[k] = pwl[(k & 31) * 32 + (k >> 5)];
    __syncthreads();
    int bId = blockIdx.x;
    float* dst; int Ho, Wo, p;
    if (bId < A3c)                          { dst = base;                                 Ho = S3c; Wo = S3c; p = bId; }
    else if (bId < A3c + 3 * S1c)           { dst = base + A3c * 1024;                    Ho = 3;   Wo = S1c; p = bId - A3c; }
    else if (bId < A3c + 3 * (S1c + S2c))   { dst = base + (A3c + 3 * S1c) * 1024;        Ho = 3;   Wo = S2c; p = bId - A3c - 3 * S1c; }
    else                                    { dst = base + (A3c + 3 * (S1c + S2c)) * 1024; Ho = 3;  Wo = S3c; p = bId - A3c - 3 * (S1c + S2c); }
    int y = p / Wo, x = p % Wo;
    float sy = fmaxf((y + 0.5f) * (64.0f / Ho) - 0.5f, 0.0f);
    int y0 = min((int)sy, 63), y1 = min(y0 + 1, 63);
    float ty = fminf(sy - (float)y0, 1.0f);
    float sx = fmaxf((x + 0.5f) * (64.0f / Wo) - 0.5f, 0.0f);
    int x0 = min((int)sx, 63), x1 = min(x0 + 1, 63);
    float tx = fminf(sx - (float)x0, 1.0f);
    float c00 = (1.f - ty) * (1.f - tx), c01 = (1.f - ty) * tx;
    float c10 = ty * (1.f - tx),         c11 = ty * tx;
    const float4* s00 = (const float4*)(wTl + (size_t)(y0 * 64 + x0) * 1024);
    const float4* s01 = (const float4*)(wTl + (size_t)(y0 * 64 + x1) * 1024);
    const float4* s10 = (const float4*)(wTl + (size_t)(y1 * 64 + x0) * 1024);
    const float4* s11 = (const float4*)(wTl + (size_t)(y1 * 64 + x1) * 1024);
    float4* op = (float4*)(dst + (size_t)p * 1024);
    int k = tid;
    float4 a = s00[k], b = s01[k], c = s10[k], d = s11[k];
    float4 pw4 = *(const float4*)&spw[k * 4];
    float4 r;
    r.x = c00*a.x + c01*b.x + c10*c.x + c11*d.x + pw4.x;
    r.y = c00*a.y + c01*b.y + c10*c.y + c11*d.y + pw4.y;
    r.z = c00*a.z + c01*b.z + c10*c.z + c11*d.z + pw4.z;
    r.w = c00*a.w + c01*b.w + c10*c.w + c11*d.w + pw4.w;
    op[k] = r;
}

// ---------------- ALL subband channel mixes for one layer, one dispatch ----------------
__global__ __launch_bounds__(256) void mix_all(
    float* __restrict__ ll3, float* __restrict__ lh3,
    float* __restrict__ lh2, float* __restrict__ lh1,
    const float* __restrict__ wl) {
    const float* wll = wl;
    const float* wh1 = wl + A3c * 1024;
    const float* wh2 = wh1 + 3 * S1c * 1024;
    const float* wh3 = wh2 + 3 * S2c * 1024;
    __shared__ float sw[1024];
    __shared__ float sv[256];
    int tid = threadIdx.x;
    int bid = blockIdx.x;
    if (bid < A3c) {
        const float* wb = wll + (size_t)bid * 1024;
        for (int k = tid; k < 1024; k += 256) sw[k] = wb[k];
        int b = tid >> 5, i = tid & 31;
        sv[tid] = ll3[((size_t)(b * 32 + i)) * A3c + bid];
        __syncthreads();
        float acc = 0.f;
        #pragma unroll
        for (int k = 0; k < 32; k++) acc += sv[b * 32 + k] * sw[k * 32 + i];
        ll3[((size_t)(b * 32 + i)) * A3c + bid] = acc;
        return;
    }
    int t = bid - A3c;
    float* hb; const float* wb; int Hs, Ws, s, y, xb; size_t bstride;
    if (t < 2 * S3c * 3) {            // L3: bpr=2
        Hs = Ws = S3c; bstride = N3c;
        int per = 2 * S3c; s = t / per; int r = t % per; y = r / 2; xb = r % 2;
        hb = lh3; wb = wh3;
    } else if ((t -= 2 * S3c * 3) < 3 * S2c * 3) {  // L2: bpr=3
        Hs = Ws = S2c; bstride = N2c;
        int per = 3 * S2c; s = t / per; int r = t % per; y = r / 3; xb = r % 3;
        hb = lh2; wb = wh2;
    } else {                           // L1: bpr=5
        t -= 3 * S2c * 3;
        Hs = Ws = S1c; bstride = N1c;
        int per = 5 * S1c; s = t / per; int r = t % per; y = r / 5; xb = r % 5;
        hb = lh1; wb = wh1;
    }
    hb += (size_t)s * bstride;
    wb += ((size_t)s * Hs + y) * 1024;
    for (int k = tid; k < 1024; k += 256) sw[k] = wb[k];
    __syncthreads();
    int q = xb * 256 + tid;
    if (q >= 8 * Ws) return;
    int b = q / Ws, x = q % Ws;
    size_t base = ((size_t)(b * 32) * Hs + y) * Ws + x;
    size_t cs = (size_t)Hs * Ws;
    float acc[32];
    #pragma unroll
    for (int o = 0; o < 32; o++) acc[o] = 0.f;
    for (int i = 0; i < 32; i++) {
        float v = hb[base + (size_t)i * cs];
        #pragma unroll
        for (int o4 = 0; o4 < 8; o4++) {
            float4 w4 = *(const float4*)&sw[i * 32 + o4 * 4];
            acc[o4*4+0] += v * w4.x; acc[o4*4+1] += v * w4.y;
            acc[o4*4+2] += v * w4.z; acc[o4*4+3] += v * w4.w;
        }
    }
    #pragma unroll
    for (int o = 0; o < 32; o++) hb[base + (size_t)o * cs] = acc[o];
}

// ---------------- head: crop + fc1 + gelu + fc2, 1 px/thread, LDS weights ----------------
__global__ __launch_bounds__(256) void head_k(
    const float* __restrict__ h, const float* __restrict__ w1, const float* __restrict__ b1,
    const float* __restrict__ w2, const float* __restrict__ b2, float* __restrict__ out) {
    __shared__ float sw1[4096];
    __shared__ float sb1[128];
    __shared__ float sw2[128];
    int tid = threadIdx.x;
    for (int k = tid; k < 4096; k += 256) sw1[k] = w1[k];
    if (tid < 128) { sb1[tid] = b1[tid]; sw2[tid] = w2[tid]; }
    __syncthreads();
    const int Hp = 258;
    int gid = blockIdx.x * 256 + tid;
    int b = gid >> 16, r = gid & 65535;
    int yy = r >> 8, xx = r & 255;
    size_t base = (size_t)b * 32 * Hp * Hp + (size_t)(yy + 1) * Hp + (xx + 1);
    float in[32];
    #pragma unroll
    for (int i = 0; i < 32; i++) in[i] = h[base + (size_t)i * Hp * Hp];
    float acc = 0.f;
    for (int j = 0; j < 128; j++) {
        float h0 = sb1[j];
        #pragma unroll
        for (int i4 = 0; i4 < 8; i4++) {
            float4 wv = *(const float4*)&sw1[j * 32 + i4 * 4];
            h0 += wv.x * in[i4*4+0] + wv.y * in[i4*4+1] + wv.z * in[i4*4+2] + wv.w * in[i4*4+3];
        }
        acc += sw2[j] * gelu_f(h0);
    }
    out[gid] = acc + b2[0];
}

extern "C" void kernel_launch(void* const* d_in, const int* in_sizes, int n_in,
                              void* d_out, int out_size, void* d_ws, size_t ws_size,
                              hipStream_t stream) {
    (void)in_sizes; (void)n_in; (void)out_size;
    const float* u    = (const float*)d_in[0];
    const float* par  = (const float*)d_in[1];
    const float* xg   = (const float*)d_in[2];
    const float* yg   = (const float*)d_in[3];
    const float* fc0w = (const float*)d_in[4];
    const float* fc0b = (const float*)d_in[5];
    const float* wcw  = (const float*)d_in[6];
    const float* pww  = (const float*)d_in[7];
    const float* pwb  = (const float*)d_in[8];
    const float* fc1w = (const float*)d_in[9];
    const float* fc1b = (const float*)d_in[10];
    const float* fc2w = (const float*)d_in[11];
    const float* fc2b = (const float*)d_in[12];
    float* out = (float*)d_out;
    float* ws  = (float*)d_ws;

    const int S1 = S1c, S2 = S2c, S3 = S3c;
    const size_t N1 = N1c, N2 = N2c, N3 = N3c;

    float* A   = ws;            // level-1 band set A: ll,lh,hl,hh (4*N1)
    float* Bb  = A   + 4 * N1;  // level-1 band set B
    float* ll2 = Bb  + 4 * N1;
    float* lh2 = ll2 + N2;
    float* hl2 = lh2 + N2;
    float* hh2 = hl2 + N2;
    float* ll3 = hh2 + N2;
    float* lh3 = ll3 + N3;
    float* hl3 = lh3 + N3;
    float* hh3 = hl3 + N3;
    float* w4  = hh3 + N3;      // 4 layers x PLc interp'd weights
    size_t needed = (size_t)(w4 + 4 * PLc - ws) * sizeof(float);
    if (ws_size < needed) return;
    float* H     = A;   // overlay: A set is dead when H is written (l=3)
    float* wTall = Bb;  // overlay: B set is dead during weight prep (16.78M <= 18.39M)

    // ---- upfront weight prep ----
    transpose_all<<<dim3(64, 64), 256, 0, stream>>>(wcw, wTall);
    int nInterp = A3c + 3 * (S1 + S2 + S3);
    interp4<<<dim3(nInterp, 4), 256, 0, stream>>>(wTall, pww, w4);

    // layer 0 analysis L1 (fc0 fused)
    dwt2d_fc0<<<dim3((S1 + 15) / 16, (S1 + 15) / 16, 256), 256, 0, stream>>>(
        u, par, xg, yg, fc0w, fc0b, A, A + N1, A + 2 * N1, A + 3 * N1);

    const int nMix = A3c + 2 * S3 * 3 + 3 * S2 * 3 + 5 * S1 * 3; // 4585

    for (int l = 0; l < 4; l++) {
        float* inb  = (l & 1) ? Bb : A;
        float* outb = (l & 1) ? A  : Bb;
        const float* wl = w4 + (size_t)l * PLc;

        dwt2d<<<dim3((S2 + 15) / 16, (S2 + 15) / 16, 256), 256, 0, stream>>>(
            inb, ll2, lh2, hl2, hh2, S1, S1, S2, S2);
        dwt2d<<<dim3((S3 + 15) / 16, (S3 + 15) / 16, 256), 256, 0, stream>>>(
            ll2, ll3, lh3, hl3, hh3, S2, S2, S3, S3);

        mix_all<<<nMix, 256, 0, stream>>>(ll3, lh3, lh2, inb + N1, wl);

        idwt2d<<<dim3((S2 + 31) / 32, (S2 + 31) / 32, 256), 256, 0, stream>>>(
            ll3, lh3, hl3, hh3, ll2, nullptr, S3, S3, S2, S2, 0);
        idwt2d<<<dim3((S1 + 31) / 32, (S1 + 31) / 32, 256), 256, 0, stream>>>(
            ll2, lh2, hl2, hh2, inb, nullptr, S2, S2, S1, S1, 0);

        if (l < 3) {
            // fused: idwt L1 (+pw-bias+gelu) -> dwt L1 of next layer
            idwt_dwt<<<dim3((S1 + 15) / 16, (S1 + 15) / 16, 256), 256, 0, stream>>>(
                inb, inb + N1, inb + 2 * N1, inb + 3 * N1,
                outb, outb + N1, outb + 2 * N1, outb + 3 * N1,
                pwb + (size_t)l * 32);
        } else {
            idwt2d<<<dim3((258 + 31) / 32, (258 + 31) / 32, 256), 256, 0, stream>>>(
                inb, inb + N1, inb + 2 * N1, inb + 3 * N1, H,
                pwb + (size_t)l * 32, S1, S1, 258, 258, 0);
        }
    }

    head_k<<<(8 * 256 * 256 + 255) / 256, 256, 0, stream>>>(H, fc1w, fc1b, fc2w, fc2b, out);
}

// Round 8
// 1140.482 us; speedup vs baseline: 1.1930x; 1.1930x over previous
//
#include <hip/hip_runtime.h>
#include <math.h>

// ---------------- wavelet filter constants (orthogonal, L=12) ----------------
#define W0f  (-0.00107730108499558f)
#define W1f  (0.004777257511010651f)
#define W2f  (0.0005538422009938016f)
#define W3f  (-0.031582039318031156f)
#define W4f  (0.02752286553001629f)
#define W5f  (0.09750160558707936f)
#define W6f  (-0.12976686756709563f)
#define W7f  (-0.22626469396516913f)
#define W8f  (0.3152503517092432f)
#define W9f  (0.7511339080215775f)
#define W10f (0.4946238903983854f)
#define W11f (0.11154074335008017f)

__constant__ float cKA0[12] = {W11f,W10f,W9f,W8f,W7f,W6f,W5f,W4f,W3f,W2f,W1f,W0f};
__constant__ float cKA1[12] = {W0f,-W1f,W2f,-W3f,W4f,-W5f,W6f,-W7f,W8f,-W9f,W10f,-W11f};
__constant__ float cKS0[12] = {W0f,W1f,W2f,W3f,W4f,W5f,W6f,W7f,W8f,W9f,W10f,W11f};
__constant__ float cKS1[12] = {-W11f,W10f,-W9f,W8f,-W7f,W6f,-W5f,W4f,-W3f,W2f,-W1f,W0f};

// problem-size constants
#define S1c 134
#define S2c 72
#define S3c 41
#define A3c 1681
#define N1c 4596736UL   // 256*134*134
#define N2c 1327104UL   // 256*72*72
#define N3c 430336UL    // 256*41*41
#define PLc 2480128UL   // per-layer interp'd weights

// fast erf (Abramowitz-Stegun 7.1.26, max abs err 1.5e-7)
__device__ __forceinline__ float gelu_f(float x) {
    float z  = x * 0.70710678118654752440f;
    float az = fabsf(z);
    float t  = __builtin_amdgcn_rcpf(1.0f + 0.3275911f * az);
    float p  = t * (0.254829592f + t * (-0.284496736f + t * (1.421413741f +
               t * (-1.453152027f + t * 1.061405429f))));
    float e  = __expf(-az * az);
    float er = copysignf(1.0f - p * e, z);
    return 0.5f * x * (1.0f + er);
}

// XCD-aware swizzle: consecutive work ids execute on the same XCD.
// Requires gridDim.x % 8 == 0 (all our grids are multiples of 256).
__device__ __forceinline__ int xcd_swizzle() {
    int bid = blockIdx.x;
    return (bid & 7) * ((int)gridDim.x >> 3) + (bid >> 3);
}

// ---------------- fused 2D analysis DWT (one level, generic, 1D swizzled grid) ----------------
__global__ __launch_bounds__(256) void dwt2d(
    const float* __restrict__ in, float* __restrict__ ll, float* __restrict__ lh,
    float* __restrict__ hl, float* __restrict__ hh, int H, int W, int Ho, int Wo,
    int tilesX, int tilesY) {
    int wg  = xcd_swizzle();
    int tpc = tilesX * tilesY;
    int c   = wg / tpc, rem = wg % tpc;
    int ty0 = (rem / tilesX) * 16;
    int tx0 = (rem % tilesX) * 16;
    const float* img = in + (size_t)c * H * W;
    __shared__ float sIn[42][44];
    __shared__ float rlo[42][17];
    __shared__ float rhi[42][17];
    int tid = threadIdx.x;
    for (int idx = tid; idx < 42 * 42; idx += 256) {
        int r = idx / 42, q = idx % 42;
        int gy = 2 * ty0 - 10 + r;
        int gx = 2 * tx0 - 10 + q;
        gy = gy < 0 ? -1 - gy : (gy >= H ? 2 * H - 1 - gy : gy);
        gx = gx < 0 ? -1 - gx : (gx >= W ? 2 * W - 1 - gx : gx);
        sIn[r][q] = img[gy * W + gx];
    }
    __syncthreads();
    for (int idx = tid; idx < 42 * 16; idx += 256) {
        int r = idx / 16, j = idx % 16;
        float alo = 0.f, ahi = 0.f;
        #pragma unroll
        for (int t = 0; t < 12; t++) {
            float v = sIn[r][2 * j + t];
            alo += v * cKA0[t];
            ahi += v * cKA1[t];
        }
        rlo[r][j] = alo; rhi[r][j] = ahi;
    }
    __syncthreads();
    int jy = tid / 16, jx = tid % 16;
    int oy = ty0 + jy, ox = tx0 + jx;
    if (oy < Ho && ox < Wo) {
        float a0 = 0.f, a1 = 0.f, a2 = 0.f, a3 = 0.f;
        #pragma unroll
        for (int t = 0; t < 12; t++) {
            float vl = rlo[2 * jy + t][jx];
            float vh = rhi[2 * jy + t][jx];
            a0 += vl * cKA0[t]; a1 += vl * cKA1[t];
            a2 += vh * cKA0[t]; a3 += vh * cKA1[t];
        }
        size_t o = (size_t)c * Ho * Wo + (size_t)oy * Wo + ox;
        ll[o] = a0; lh[o] = a1; hl[o] = a2; hh[o] = a3;
    }
}

// ---------------- layer-0 DWT L1 with fc0 + reflect-pad fused in (swizzled) ----------------
__global__ __launch_bounds__(256) void dwt2d_fc0(
    const float* __restrict__ u, const float* __restrict__ par,
    const float* __restrict__ xg, const float* __restrict__ yg,
    const float* __restrict__ fw, const float* __restrict__ fb,
    float* __restrict__ ll, float* __restrict__ lh,
    float* __restrict__ hl, float* __restrict__ hh) {
    const int Hd = 258, S = 256, Ho = S1c, Wo = S1c, tilesX = 9;
    int wg  = xcd_swizzle();
    int tpc = tilesX * tilesX;
    int c   = wg / tpc, rem = wg % tpc;
    int b   = c >> 5, o = c & 31;
    int ty0 = (rem / tilesX) * 16;
    int tx0 = (rem % tilesX) * 16;
    float w0 = fw[o*4], w1 = fw[o*4+1], w2 = fw[o*4+2], w3 = fw[o*4+3], bv = fb[o];
    __shared__ float sIn[42][44];
    __shared__ float rlo[42][17];
    __shared__ float rhi[42][17];
    int tid = threadIdx.x;
    for (int idx = tid; idx < 42 * 42; idx += 256) {
        int r = idx / 42, q = idx % 42;
        int gy = 2 * ty0 - 10 + r;
        int gx = 2 * tx0 - 10 + q;
        gy = gy < 0 ? -1 - gy : (gy >= Hd ? 2 * Hd - 1 - gy : gy);
        gx = gx < 0 ? -1 - gx : (gx >= Hd ? 2 * Hd - 1 - gx : gx);
        int iy = gy - 1; iy = iy < 0 ? -iy : (iy >= S ? 2 * S - 2 - iy : iy);
        int ix = gx - 1; ix = ix < 0 ? -ix : (ix >= S ? 2 * S - 2 - ix : ix);
        float vu = u  [(b * S + iy) * S + ix];
        float vp = par[(b * S + iy) * S + ix];
        sIn[r][q] = w0 * vu + w1 * vp + w2 * xg[b * S + iy] + w3 * yg[b * S + ix] + bv;
    }
    __syncthreads();
    for (int idx = tid; idx < 42 * 16; idx += 256) {
        int r = idx / 16, j = idx % 16;
        float alo = 0.f, ahi = 0.f;
        #pragma unroll
        for (int t = 0; t < 12; t++) {
            float v = sIn[r][2 * j + t];
            alo += v * cKA0[t];
            ahi += v * cKA1[t];
        }
        rlo[r][j] = alo; rhi[r][j] = ahi;
    }
    __syncthreads();
    int jy = tid / 16, jx = tid % 16;
    int oy = ty0 + jy, ox = tx0 + jx;
    if (oy < Ho && ox < Wo) {
        float a0 = 0.f, a1 = 0.f, a2 = 0.f, a3 = 0.f;
        #pragma unroll
        for (int t = 0; t < 12; t++) {
            float vl = rlo[2 * jy + t][jx];
            float vh = rhi[2 * jy + t][jx];
            a0 += vl * cKA0[t]; a1 += vl * cKA1[t];
            a2 += vh * cKA0[t]; a3 += vh * cKA1[t];
        }
        size_t oo = (size_t)c * Ho * Wo + (size_t)oy * Wo + ox;
        ll[oo] = a0; lh[oo] = a1; hl[oo] = a2; hh[oo] = a3;
    }
}

// ---------------- fused 2D synthesis IDWT (optional per-channel bias + gelu, swizzled) ----------------
__global__ __launch_bounds__(256) void idwt2d(
    const float* __restrict__ ll, const float* __restrict__ lh,
    const float* __restrict__ hl, const float* __restrict__ hh,
    float* __restrict__ out, const float* __restrict__ pb,
    int h, int w, int Oh, int Ow, int do_gelu, int tilesX, int tilesY) {
    int wg  = xcd_swizzle();
    int tpc = tilesX * tilesY;
    int c   = wg / tpc, rem = wg % tpc;
    int my0 = (rem / tilesX) * 16;
    int nx0 = (rem % tilesX) * 16;
    __shared__ float sll[21][22], slh[21][22], shl[21][22], shh[21][22];
    __shared__ float sxl[32][22], sxh[32][22];
    int tid = threadIdx.x;
    size_t cb = (size_t)c * h * w;
    float bias = pb ? pb[c & 31] : 0.f;
    for (int idx = tid; idx < 21 * 21; idx += 256) {
        int r = idx / 21, q = idx % 21;
        int gy = min(my0 + r, h - 1);
        int gx = min(nx0 + q, w - 1);
        size_t g = cb + (size_t)gy * w + gx;
        sll[r][q] = ll[g]; slh[r][q] = lh[g];
        shl[r][q] = hl[g]; shh[r][q] = hh[g];
    }
    __syncthreads();
    for (int idx = tid; idx < 32 * 21; idx += 256) {
        int r = idx / 21, q = idx % 21;
        int mp = r >> 1, p = r & 1;
        float al = 0.f, ah = 0.f;
        #pragma unroll
        for (int s = 0; s < 6; s++) {
            float k0 = cKS0[2 * s + 1 - p];
            float k1 = cKS1[2 * s + 1 - p];
            al += sll[mp + s][q] * k0 + slh[mp + s][q] * k1;
            ah += shl[mp + s][q] * k0 + shh[mp + s][q] * k1;
        }
        sxl[r][q] = al; sxh[r][q] = ah;
    }
    __syncthreads();
    for (int idx = tid; idx < 32 * 32; idx += 256) {
        int r = idx / 32, q2 = idx % 32;
        int np = q2 >> 1, q = q2 & 1;
        int oy = 2 * my0 + r, ox = 2 * nx0 + q2;
        if (oy < Oh && ox < Ow) {
            float a = bias;
            #pragma unroll
            for (int s = 0; s < 6; s++) {
                float k0 = cKS0[2 * s + 1 - q];
                float k1 = cKS1[2 * s + 1 - q];
                a += sxl[r][np + s] * k0 + sxh[r][np + s] * k1;
            }
            if (do_gelu) a = gelu_f(a);
            out[(size_t)c * Oh * Ow + (size_t)oy * Ow + ox] = a;
        }
    }
}

// ---------------- transpose all 4 layers: [l][1024 io][4096 yx] -> [l][4096 yx][1024 io] ----------------
__global__ __launch_bounds__(256) void transpose_all(
    const float* __restrict__ w, float* __restrict__ wT) {
    __shared__ float t[64][65];
    int l  = blockIdx.y >> 4;
    int by = (blockIdx.y & 15) * 64; // io
    int bx = blockIdx.x * 64;        // yx
    const float* wl = w  + (size_t)l * 4194304;
    float* wTl      = wT + (size_t)l * 4194304;
    int tid = threadIdx.x;
    for (int idx = tid; idx < 4096; idx += 256) {
        int r = idx >> 6, q = idx & 63;
        t[r][q] = wl[(size_t)(by + r) * 4096 + bx + q];
    }
    __syncthreads();
    for (int idx = tid; idx < 4096; idx += 256) {
        int r = idx >> 6, q = idx & 63;
        wTl[(size_t)(bx + r) * 1024 + by + q] = t[q][r];
    }
}

// ---------------- bilinear interp of weights for all 4 layers, + pw folded in ----------------
__global__ __launch_bounds__(256) void interp4(
    const float* __restrict__ wT, const float* __restrict__ pw,
    float* __restrict__ wout) {
    int l = blockIdx.y;
    const float* wTl = wT + (size_t)l * 4194304;
    const float* pwl = pw + (size_t)l * 1024;
    float* base = wout + (size_t)l * PLc;
    __shared__ float spw[1024]; // transposed pw: spw[i*32+o] = pw[o*32+i]
    int tid = threadIdx.x;
    for (int k = tid; k < 1024; k += 256) spw[k] = pwl[(k & 31) * 32 + (k >> 5)];
    __syncthreads();
    int bId = blockIdx.x;
    float* dst; int Ho, Wo, p;
    if (bId < A3c)                          { dst = base;                                 Ho = S3c; Wo = S3c; p = bId; }
    else if (bId < A3c + 3 * S1c)           { dst = base + A3c * 1024;                    Ho = 3;   Wo = S1c; p = bId - A3c; }
    else if (bId < A3c + 3 * (S1c + S2c))   { dst = base + (A3c + 3 * S1c) * 1024;        Ho = 3;   Wo = S2c; p = bId - A3c - 3 * S1c; }
    else                                    { dst = base + (A3c + 3 * (S1c + S2c)) * 1024; Ho = 3;  Wo = S3c; p = bId - A3c - 3 * (S1c + S2c); }
    int y = p / Wo, x = p % Wo;
    float sy = fmaxf((y + 0.5f) * (64.0f / Ho) - 0.5f, 0.0f);
    int y0 = min((int)sy, 63), y1 = min(y0 + 1, 63);
    float ty = fminf(sy - (float)y0, 1.0f);
    float sx = fmaxf((x + 0.5f) * (64.0f / Wo) - 0.5f, 0.0f);
    int x0 = min((int)sx, 63), x1 = min(x0 + 1, 63);
    float tx = fminf(sx - (float)x0, 1.0f);
    float c00 = (1.f - ty) * (1.f - tx), c01 = (1.f - ty) * tx;
    float c10 = ty * (1.f - tx),         c11 = ty * tx;
    const float4* s00 = (const float4*)(wTl + (size_t)(y0 * 64 + x0) * 1024);
    const float4* s01 = (const float4*)(wTl + (size_t)(y0 * 64 + x1) * 1024);
    const float4* s10 = (const float4*)(wTl + (size_t)(y1 * 64 + x0) * 1024);
    const float4* s11 = (const float4*)(wTl + (size_t)(y1 * 64 + x1) * 1024);
    float4* op = (float4*)(dst + (size_t)p * 1024);
    int k = tid;
    float4 a = s00[k], b = s01[k], c = s10[k], d = s11[k];
    float4 pw4 = *(const float4*)&spw[k * 4];
    float4 r;
    r.x = c00*a.x + c01*b.x + c10*c.x + c11*d.x + pw4.x;
    r.y = c00*a.y + c01*b.y + c10*c.y + c11*d.y + pw4.y;
    r.z = c00*a.z + c01*b.z + c10*c.z + c11*d.z + pw4.z;
    r.w = c00*a.w + c01*b.w + c10*c.w + c11*d.w + pw4.w;
    op[k] = r;
}

// ---------------- ALL subband channel mixes for one layer, one dispatch ----------------
__global__ __launch_bounds__(256) void mix_all(
    float* __restrict__ ll3, float* __restrict__ lh3,
    float* __restrict__ lh2, float* __restrict__ lh1,
    const float* __restrict__ wl) {
    const float* wll = wl;
    const float* wh1 = wl + A3c * 1024;
    const float* wh2 = wh1 + 3 * S1c * 1024;
    const float* wh3 = wh2 + 3 * S2c * 1024;
    __shared__ float sw[1024];
    __shared__ float sv[256];
    int tid = threadIdx.x;
    int bid = blockIdx.x;
    if (bid < A3c) {
        const float* wb = wll + (size_t)bid * 1024;
        for (int k = tid; k < 1024; k += 256) sw[k] = wb[k];
        int b = tid >> 5, i = tid & 31;
        sv[tid] = ll3[((size_t)(b * 32 + i)) * A3c + bid];
        __syncthreads();
        float acc = 0.f;
        #pragma unroll
        for (int k = 0; k < 32; k++) acc += sv[b * 32 + k] * sw[k * 32 + i];
        ll3[((size_t)(b * 32 + i)) * A3c + bid] = acc;
        return;
    }
    int t = bid - A3c;
    float* hb; const float* wb; int Hs, Ws, s, y, xb; size_t bstride;
    if (t < 2 * S3c * 3) {            // L3: bpr=2
        Hs = Ws = S3c; bstride = N3c;
        int per = 2 * S3c; s = t / per; int r = t % per; y = r / 2; xb = r % 2;
        hb = lh3; wb = wh3;
    } else if ((t -= 2 * S3c * 3) < 3 * S2c * 3) {  // L2: bpr=3
        Hs = Ws = S2c; bstride = N2c;
        int per = 3 * S2c; s = t / per; int r = t % per; y = r / 3; xb = r % 3;
        hb = lh2; wb = wh2;
    } else {                           // L1: bpr=5
        t -= 3 * S2c * 3;
        Hs = Ws = S1c; bstride = N1c;
        int per = 5 * S1c; s = t / per; int r = t % per; y = r / 5; xb = r % 5;
        hb = lh1; wb = wh1;
    }
    hb += (size_t)s * bstride;
    wb += ((size_t)s * Hs + y) * 1024;
    for (int k = tid; k < 1024; k += 256) sw[k] = wb[k];
    __syncthreads();
    int q = xb * 256 + tid;
    if (q >= 8 * Ws) return;
    int b = q / Ws, x = q % Ws;
    size_t base = ((size_t)(b * 32) * Hs + y) * Ws + x;
    size_t cs = (size_t)Hs * Ws;
    float acc[32];
    #pragma unroll
    for (int o = 0; o < 32; o++) acc[o] = 0.f;
    for (int i = 0; i < 32; i++) {
        float v = hb[base + (size_t)i * cs];
        #pragma unroll
        for (int o4 = 0; o4 < 8; o4++) {
            float4 w4 = *(const float4*)&sw[i * 32 + o4 * 4];
            acc[o4*4+0] += v * w4.x; acc[o4*4+1] += v * w4.y;
            acc[o4*4+2] += v * w4.z; acc[o4*4+3] += v * w4.w;
        }
    }
    #pragma unroll
    for (int o = 0; o < 32; o++) hb[base + (size_t)o * cs] = acc[o];
}

// ---------------- head: crop + fc1 + gelu + fc2, 1 px/thread, LDS weights ----------------
__global__ __launch_bounds__(256) void head_k(
    const float* __restrict__ h, const float* __restrict__ w1, const float* __restrict__ b1,
    const float* __restrict__ w2, const float* __restrict__ b2, float* __restrict__ out) {
    __shared__ float sw1[4096];
    __shared__ float sb1[128];
    __shared__ float sw2[128];
    int tid = threadIdx.x;
    for (int k = tid; k < 4096; k += 256) sw1[k] = w1[k];
    if (tid < 128) { sb1[tid] = b1[tid]; sw2[tid] = w2[tid]; }
    __syncthreads();
    const int Hp = 258;
    int gid = blockIdx.x * 256 + tid;
    int b = gid >> 16, r = gid & 65535;
    int yy = r >> 8, xx = r & 255;
    size_t base = (size_t)b * 32 * Hp * Hp + (size_t)(yy + 1) * Hp + (xx + 1);
    float in[32];
    #pragma unroll
    for (int i = 0; i < 32; i++) in[i] = h[base + (size_t)i * Hp * Hp];
    float acc = 0.f;
    for (int j = 0; j < 128; j++) {
        float h0 = sb1[j];
        #pragma unroll
        for (int i4 = 0; i4 < 8; i4++) {
            float4 wv = *(const float4*)&sw1[j * 32 + i4 * 4];
            h0 += wv.x * in[i4*4+0] + wv.y * in[i4*4+1] + wv.z * in[i4*4+2] + wv.w * in[i4*4+3];
        }
        acc += sw2[j] * gelu_f(h0);
    }
    out[gid] = acc + b2[0];
}

extern "C" void kernel_launch(void* const* d_in, const int* in_sizes, int n_in,
                              void* d_out, int out_size, void* d_ws, size_t ws_size,
                              hipStream_t stream) {
    (void)in_sizes; (void)n_in; (void)out_size;
    const float* u    = (const float*)d_in[0];
    const float* par  = (const float*)d_in[1];
    const float* xg   = (const float*)d_in[2];
    const float* yg   = (const float*)d_in[3];
    const float* fc0w = (const float*)d_in[4];
    const float* fc0b = (const float*)d_in[5];
    const float* wcw  = (const float*)d_in[6];
    const float* pww  = (const float*)d_in[7];
    const float* pwb  = (const float*)d_in[8];
    const float* fc1w = (const float*)d_in[9];
    const float* fc1b = (const float*)d_in[10];
    const float* fc2w = (const float*)d_in[11];
    const float* fc2b = (const float*)d_in[12];
    float* out = (float*)d_out;
    float* ws  = (float*)d_ws;

    const int Hp = 258;
    const size_t HW = (size_t)Hp * Hp;
    const size_t NH = 256 * HW;
    const int S1 = S1c, S2 = S2c, S3 = S3c;
    const size_t N1 = N1c, N2 = N2c, N3 = N3c;

    float* H   = ws;
    float* ll1 = H   + NH;
    float* lh1 = ll1 + N1;
    float* hl1 = lh1 + N1;
    float* hh1 = hl1 + N1;
    float* ll2 = hh1 + N1;
    float* lh2 = ll2 + N2;
    float* hl2 = lh2 + N2;
    float* hh2 = hl2 + N2;
    float* ll3 = hh2 + N2;
    float* lh3 = ll3 + N3;
    float* hl3 = lh3 + N3;
    float* hh3 = hl3 + N3;
    float* w4  = hh3 + N3;                  // 4 layers x PLc interp'd weights
    size_t needed = (size_t)(w4 + 4 * PLc - ws) * sizeof(float);
    if (ws_size < needed) return;
    // wT scratch for all 4 layers overlays lh1.. (dead until dwt L1 writes it)
    float* wTall = lh1;

    // tile counts
    const int tX1 = 9, tX2 = 5, tX3 = 3;        // dwt 16x16-out tiles
    const int iX3 = 3, iX2 = 5, iX1 = 9;        // idwt 32x32-out tiles (to 72/134/258)

    // ---- upfront weight prep ----
    transpose_all<<<dim3(64, 64), 256, 0, stream>>>(wcw, wTall);
    int nInterp = A3c + 3 * (S1 + S2 + S3);
    interp4<<<dim3(nInterp, 4), 256, 0, stream>>>(wTall, pww, w4);

    const int nMix = A3c + 2 * S3 * 3 + 3 * S2 * 3 + 5 * S1 * 3; // 4585

    for (int l = 0; l < 4; l++) {
        const float* wl = w4 + (size_t)l * PLc;

        if (l == 0) {
            dwt2d_fc0<<<tX1 * tX1 * 256, 256, 0, stream>>>(
                u, par, xg, yg, fc0w, fc0b, ll1, lh1, hl1, hh1);
        } else {
            dwt2d<<<tX1 * tX1 * 256, 256, 0, stream>>>(
                H, ll1, lh1, hl1, hh1, Hp, Hp, S1, S1, tX1, tX1);
        }
        dwt2d<<<tX2 * tX2 * 256, 256, 0, stream>>>(
            ll1, ll2, lh2, hl2, hh2, S1, S1, S2, S2, tX2, tX2);
        dwt2d<<<tX3 * tX3 * 256, 256, 0, stream>>>(
            ll2, ll3, lh3, hl3, hh3, S2, S2, S3, S3, tX3, tX3);

        mix_all<<<nMix, 256, 0, stream>>>(ll3, lh3, lh2, lh1, wl);

        idwt2d<<<iX3 * iX3 * 256, 256, 0, stream>>>(
            ll3, lh3, hl3, hh3, ll2, nullptr, S3, S3, S2, S2, 0, iX3, iX3);
        idwt2d<<<iX2 * iX2 * 256, 256, 0, stream>>>(
            ll2, lh2, hl2, hh2, ll1, nullptr, S2, S2, S1, S1, 0, iX2, iX2);
        idwt2d<<<iX1 * iX1 * 256, 256, 0, stream>>>(
            ll1, lh1, hl1, hh1, H, pwb + (size_t)l * 32, S1, S1, Hp, Hp,
            (l < 3) ? 1 : 0, iX1, iX1);
    }

    head_k<<<(8 * 256 * 256 + 255) / 256, 256, 0, stream>>>(H, fc1w, fc1b, fc2w, fc2b, out);
}

// Round 9
// 1114.106 us; speedup vs baseline: 1.2213x; 1.0237x over previous
//
#include <hip/hip_runtime.h>
#include <math.h>

// ---------------- wavelet filter constants (orthogonal, L=12) ----------------
#define W0f  (-0.00107730108499558f)
#define W1f  (0.004777257511010651f)
#define W2f  (0.0005538422009938016f)
#define W3f  (-0.031582039318031156f)
#define W4f  (0.02752286553001629f)
#define W5f  (0.09750160558707936f)
#define W6f  (-0.12976686756709563f)
#define W7f  (-0.22626469396516913f)
#define W8f  (0.3152503517092432f)
#define W9f  (0.7511339080215775f)
#define W10f (0.4946238903983854f)
#define W11f (0.11154074335008017f)

__constant__ float cKA0[12] = {W11f,W10f,W9f,W8f,W7f,W6f,W5f,W4f,W3f,W2f,W1f,W0f};
__constant__ float cKA1[12] = {W0f,-W1f,W2f,-W3f,W4f,-W5f,W6f,-W7f,W8f,-W9f,W10f,-W11f};
__constant__ float cKS0[12] = {W0f,W1f,W2f,W3f,W4f,W5f,W6f,W7f,W8f,W9f,W10f,W11f};
__constant__ float cKS1[12] = {-W11f,W10f,-W9f,W8f,-W7f,W6f,-W5f,W4f,-W3f,W2f,-W1f,W0f};

// problem-size constants
#define S1c 134
#define S2c 72
#define S3c 41
#define A3c 1681
#define N1c 4596736UL   // 256*134*134
#define N2c 1327104UL   // 256*72*72
#define N3c 430336UL    // 256*41*41
#define PLc 2480128UL   // per-layer interp'd weights

// fast erf (Abramowitz-Stegun 7.1.26, max abs err 1.5e-7)
__device__ __forceinline__ float gelu_f(float x) {
    float z  = x * 0.70710678118654752440f;
    float az = fabsf(z);
    float t  = __builtin_amdgcn_rcpf(1.0f + 0.3275911f * az);
    float p  = t * (0.254829592f + t * (-0.284496736f + t * (1.421413741f +
               t * (-1.453152027f + t * 1.061405429f))));
    float e  = __expf(-az * az);
    float er = copysignf(1.0f - p * e, z);
    return 0.5f * x * (1.0f + er);
}

// XCD-aware swizzle: consecutive work ids execute on the same XCD.
// Requires gridDim.x % 8 == 0 (all our grids are multiples of 256).
__device__ __forceinline__ int xcd_swizzle() {
    int bid = blockIdx.x;
    return (bid & 7) * ((int)gridDim.x >> 3) + (bid >> 3);
}

// ---------------- fused 2D analysis DWT (one level, generic, 1D swizzled grid) ----------------
// sIn stride 45 (odd): wave's four 16-lane groups land on mixed-parity bank offsets -> no 4-way conflict
__global__ __launch_bounds__(256) void dwt2d(
    const float* __restrict__ in, float* __restrict__ ll, float* __restrict__ lh,
    float* __restrict__ hl, float* __restrict__ hh, int H, int W, int Ho, int Wo,
    int tilesX, int tilesY) {
    int wg  = xcd_swizzle();
    int tpc = tilesX * tilesY;
    int c   = wg / tpc, rem = wg % tpc;
    int ty0 = (rem / tilesX) * 16;
    int tx0 = (rem % tilesX) * 16;
    const float* img = in + (size_t)c * H * W;
    __shared__ float sIn[42][45];
    __shared__ float rlo[42][17];
    __shared__ float rhi[42][17];
    int tid = threadIdx.x;
    for (int idx = tid; idx < 42 * 42; idx += 256) {
        int r = idx / 42, q = idx % 42;
        int gy = 2 * ty0 - 10 + r;
        int gx = 2 * tx0 - 10 + q;
        gy = gy < 0 ? -1 - gy : (gy >= H ? 2 * H - 1 - gy : gy);
        gx = gx < 0 ? -1 - gx : (gx >= W ? 2 * W - 1 - gx : gx);
        sIn[r][q] = img[gy * W + gx];
    }
    __syncthreads();
    for (int idx = tid; idx < 42 * 16; idx += 256) {
        int r = idx / 16, j = idx % 16;
        float alo = 0.f, ahi = 0.f;
        #pragma unroll
        for (int t = 0; t < 12; t++) {
            float v = sIn[r][2 * j + t];
            alo += v * cKA0[t];
            ahi += v * cKA1[t];
        }
        rlo[r][j] = alo; rhi[r][j] = ahi;
    }
    __syncthreads();
    int jy = tid / 16, jx = tid % 16;
    int oy = ty0 + jy, ox = tx0 + jx;
    if (oy < Ho && ox < Wo) {
        float a0 = 0.f, a1 = 0.f, a2 = 0.f, a3 = 0.f;
        #pragma unroll
        for (int t = 0; t < 12; t++) {
            float vl = rlo[2 * jy + t][jx];
            float vh = rhi[2 * jy + t][jx];
            a0 += vl * cKA0[t]; a1 += vl * cKA1[t];
            a2 += vh * cKA0[t]; a3 += vh * cKA1[t];
        }
        size_t o = (size_t)c * Ho * Wo + (size_t)oy * Wo + ox;
        ll[o] = a0; lh[o] = a1; hl[o] = a2; hh[o] = a3;
    }
}

// ---------------- layer-0 DWT L1 with fc0 + reflect-pad fused in (swizzled) ----------------
__global__ __launch_bounds__(256) void dwt2d_fc0(
    const float* __restrict__ u, const float* __restrict__ par,
    const float* __restrict__ xg, const float* __restrict__ yg,
    const float* __restrict__ fw, const float* __restrict__ fb,
    float* __restrict__ ll, float* __restrict__ lh,
    float* __restrict__ hl, float* __restrict__ hh) {
    const int Hd = 258, S = 256, Ho = S1c, Wo = S1c, tilesX = 9;
    int wg  = xcd_swizzle();
    int tpc = tilesX * tilesX;
    int c   = wg / tpc, rem = wg % tpc;
    int b   = c >> 5, o = c & 31;
    int ty0 = (rem / tilesX) * 16;
    int tx0 = (rem % tilesX) * 16;
    float w0 = fw[o*4], w1 = fw[o*4+1], w2 = fw[o*4+2], w3 = fw[o*4+3], bv = fb[o];
    __shared__ float sIn[42][45];
    __shared__ float rlo[42][17];
    __shared__ float rhi[42][17];
    int tid = threadIdx.x;
    for (int idx = tid; idx < 42 * 42; idx += 256) {
        int r = idx / 42, q = idx % 42;
        int gy = 2 * ty0 - 10 + r;
        int gx = 2 * tx0 - 10 + q;
        gy = gy < 0 ? -1 - gy : (gy >= Hd ? 2 * Hd - 1 - gy : gy);
        gx = gx < 0 ? -1 - gx : (gx >= Hd ? 2 * Hd - 1 - gx : gx);
        int iy = gy - 1; iy = iy < 0 ? -iy : (iy >= S ? 2 * S - 2 - iy : iy);
        int ix = gx - 1; ix = ix < 0 ? -ix : (ix >= S ? 2 * S - 2 - ix : ix);
        float vu = u  [(b * S + iy) * S + ix];
        float vp = par[(b * S + iy) * S + ix];
        sIn[r][q] = w0 * vu + w1 * vp + w2 * xg[b * S + iy] + w3 * yg[b * S + ix] + bv;
    }
    __syncthreads();
    for (int idx = tid; idx < 42 * 16; idx += 256) {
        int r = idx / 16, j = idx % 16;
        float alo = 0.f, ahi = 0.f;
        #pragma unroll
        for (int t = 0; t < 12; t++) {
            float v = sIn[r][2 * j + t];
            alo += v * cKA0[t];
            ahi += v * cKA1[t];
        }
        rlo[r][j] = alo; rhi[r][j] = ahi;
    }
    __syncthreads();
    int jy = tid / 16, jx = tid % 16;
    int oy = ty0 + jy, ox = tx0 + jx;
    if (oy < Ho && ox < Wo) {
        float a0 = 0.f, a1 = 0.f, a2 = 0.f, a3 = 0.f;
        #pragma unroll
        for (int t = 0; t < 12; t++) {
            float vl = rlo[2 * jy + t][jx];
            float vh = rhi[2 * jy + t][jx];
            a0 += vl * cKA0[t]; a1 += vl * cKA1[t];
            a2 += vh * cKA0[t]; a3 += vh * cKA1[t];
        }
        size_t oo = (size_t)c * Ho * Wo + (size_t)oy * Wo + ox;
        ll[oo] = a0; lh[oo] = a1; hl[oo] = a2; hh[oo] = a3;
    }
}

// ---------------- fused 2D synthesis IDWT (optional per-channel bias + gelu, swizzled) ----------------
__global__ __launch_bounds__(256) void idwt2d(
    const float* __restrict__ ll, const float* __restrict__ lh,
    const float* __restrict__ hl, const float* __restrict__ hh,
    float* __restrict__ out, const float* __restrict__ pb,
    int h, int w, int Oh, int Ow, int do_gelu, int tilesX, int tilesY) {
    int wg  = xcd_swizzle();
    int tpc = tilesX * tilesY;
    int c   = wg / tpc, rem = wg % tpc;
    int my0 = (rem / tilesX) * 16;
    int nx0 = (rem % tilesX) * 16;
    __shared__ float sll[21][22], slh[21][22], shl[21][22], shh[21][22];
    __shared__ float sxl[32][22], sxh[32][22];
    int tid = threadIdx.x;
    size_t cb = (size_t)c * h * w;
    float bias = pb ? pb[c & 31] : 0.f;
    for (int idx = tid; idx < 21 * 21; idx += 256) {
        int r = idx / 21, q = idx % 21;
        int gy = min(my0 + r, h - 1);
        int gx = min(nx0 + q, w - 1);
        size_t g = cb + (size_t)gy * w + gx;
        sll[r][q] = ll[g]; slh[r][q] = lh[g];
        shl[r][q] = hl[g]; shh[r][q] = hh[g];
    }
    __syncthreads();
    for (int idx = tid; idx < 32 * 21; idx += 256) {
        int r = idx / 21, q = idx % 21;
        int mp = r >> 1, p = r & 1;
        float al = 0.f, ah = 0.f;
        #pragma unroll
        for (int s = 0; s < 6; s++) {
            float k0 = cKS0[2 * s + 1 - p];
            float k1 = cKS1[2 * s + 1 - p];
            al += sll[mp + s][q] * k0 + slh[mp + s][q] * k1;
            ah += shl[mp + s][q] * k0 + shh[mp + s][q] * k1;
        }
        sxl[r][q] = al; sxh[r][q] = ah;
    }
    __syncthreads();
    for (int idx = tid; idx < 32 * 32; idx += 256) {
        int r = idx / 32, q2 = idx % 32;
        int np = q2 >> 1, q = q2 & 1;
        int oy = 2 * my0 + r, ox = 2 * nx0 + q2;
        if (oy < Oh && ox < Ow) {
            float a = bias;
            #pragma unroll
            for (int s = 0; s < 6; s++) {
                float k0 = cKS0[2 * s + 1 - q];
                float k1 = cKS1[2 * s + 1 - q];
                a += sxl[r][np + s] * k0 + sxh[r][np + s] * k1;
            }
            if (do_gelu) a = gelu_f(a);
            out[(size_t)c * Oh * Ow + (size_t)oy * Ow + ox] = a;
        }
    }
}

// ---------------- transpose all 4 layers: [l][1024 io][4096 yx] -> [l][4096 yx][1024 io] ----------------
__global__ __launch_bounds__(256) void transpose_all(
    const float* __restrict__ w, float* __restrict__ wT) {
    __shared__ float t[64][65];
    int l  = blockIdx.y >> 4;
    int by = (blockIdx.y & 15) * 64; // io
    int bx = blockIdx.x * 64;        // yx
    const float* wl = w  + (size_t)l * 4194304;
    float* wTl      = wT + (size_t)l * 4194304;
    int tid = threadIdx.x;
    for (int idx = tid; idx < 4096; idx += 256) {
        int r = idx >> 6, q = idx & 63;
        t[r][q] = wl[(size_t)(by + r) * 4096 + bx + q];
    }
    __syncthreads();
    for (int idx = tid; idx < 4096; idx += 256) {
        int r = idx >> 6, q = idx & 63;
        wTl[(size_t)(bx + r) * 1024 + by + q] = t[q][r];
    }
}

// ---------------- bilinear interp of weights for all 4 layers, + pw folded in ----------------
__global__ __launch_bounds__(256) void interp4(
    const float* __restrict__ wT, const float* __restrict__ pw,
    float* __restrict__ wout) {
    int l = blockIdx.y;
    const float* wTl = wT + (size_t)l * 4194304;
    const float* pwl = pw + (size_t)l * 1024;
    float* base = wout + (size_t)l * PLc;
    __shared__ float spw[1024]; // transposed pw: spw[i*32+o] = pw[o*32+i]
    int tid = threadIdx.x;
    for (int k = tid; k < 1024; k += 256) spw[k] = pwl[(k & 31) * 32 + (k >> 5)];
    __syncthreads();
    int bId = blockIdx.x;
    float* dst; int Ho, Wo, p;
    if (bId < A3c)                          { dst = base;                                 Ho = S3c; Wo = S3c; p = bId; }
    else if (bId < A3c + 3 * S1c)           { dst = base + A3c * 1024;                    Ho = 3;   Wo = S1c; p = bId - A3c; }
    else if (bId < A3c + 3 * (S1c + S2c))   { dst = base + (A3c + 3 * S1c) * 1024;        Ho = 3;   Wo = S2c; p = bId - A3c - 3 * S1c; }
    else                                    { dst = base + (A3c + 3 * (S1c + S2c)) * 1024; Ho = 3;  Wo = S3c; p = bId - A3c - 3 * (S1c + S2c); }
    int y = p / Wo, x = p % Wo;
    float sy = fmaxf((y + 0.5f) * (64.0f / Ho) - 0.5f, 0.0f);
    int y0 = min((int)sy, 63), y1 = min(y0 + 1, 63);
    float ty = fminf(sy - (float)y0, 1.0f);
    float sx = fmaxf((x + 0.5f) * (64.0f / Wo) - 0.5f, 0.0f);
    int x0 = min((int)sx, 63), x1 = min(x0 + 1, 63);
    float tx = fminf(sx - (float)x0, 1.0f);
    float c00 = (1.f - ty) * (1.f - tx), c01 = (1.f - ty) * tx;
    float c10 = ty * (1.f - tx),         c11 = ty * tx;
    const float4* s00 = (const float4*)(wTl + (size_t)(y0 * 64 + x0) * 1024);
    const float4* s01 = (const float4*)(wTl + (size_t)(y0 * 64 + x1) * 1024);
    const float4* s10 = (const float4*)(wTl + (size_t)(y1 * 64 + x0) * 1024);
    const float4* s11 = (const float4*)(wTl + (size_t)(y1 * 64 + x1) * 1024);
    float4* op = (float4*)(dst + (size_t)p * 1024);
    int k = tid;
    float4 a = s00[k], b = s01[k], c = s10[k], d = s11[k];
    float4 pw4 = *(const float4*)&spw[k * 4];
    float4 r;
    r.x = c00*a.x + c01*b.x + c10*c.x + c11*d.x + pw4.x;
    r.y = c00*a.y + c01*b.y + c10*c.y + c11*d.y + pw4.y;
    r.z = c00*a.z + c01*b.z + c10*c.z + c11*d.z + pw4.z;
    r.w = c00*a.w + c01*b.w + c10*c.w + c11*d.w + pw4.w;
    op[k] = r;
}

// ---------------- ALL subband channel mixes for one layer, one dispatch ----------------
__global__ __launch_bounds__(256) void mix_all(
    float* __restrict__ ll3, float* __restrict__ lh3,
    float* __restrict__ lh2, float* __restrict__ lh1,
    const float* __restrict__ wl) {
    const float* wll = wl;
    const float* wh1 = wl + A3c * 1024;
    const float* wh2 = wh1 + 3 * S1c * 1024;
    const float* wh3 = wh2 + 3 * S2c * 1024;
    __shared__ float sw[1024];
    __shared__ float sv[256];
    int tid = threadIdx.x;
    int bid = blockIdx.x;
    if (bid < A3c) {
        const float* wb = wll + (size_t)bid * 1024;
        for (int k = tid; k < 1024; k += 256) sw[k] = wb[k];
        int b = tid >> 5, i = tid & 31;
        sv[tid] = ll3[((size_t)(b * 32 + i)) * A3c + bid];
        __syncthreads();
        float acc = 0.f;
        #pragma unroll
        for (int k = 0; k < 32; k++) acc += sv[b * 32 + k] * sw[k * 32 + i];
        ll3[((size_t)(b * 32 + i)) * A3c + bid] = acc;
        return;
    }
    int t = bid - A3c;
    float* hb; const float* wb; int Hs, Ws, s, y, xb; size_t bstride;
    if (t < 2 * S3c * 3) {            // L3: bpr=2
        Hs = Ws = S3c; bstride = N3c;
        int per = 2 * S3c; s = t / per; int r = t % per; y = r / 2; xb = r % 2;
        hb = lh3; wb = wh3;
    } else if ((t -= 2 * S3c * 3) < 3 * S2c * 3) {  // L2: bpr=3
        Hs = Ws = S2c; bstride = N2c;
        int per = 3 * S2c; s = t / per; int r = t % per; y = r / 3; xb = r % 3;
        hb = lh2; wb = wh2;
    } else {                           // L1: bpr=5
        t -= 3 * S2c * 3;
        Hs = Ws = S1c; bstride = N1c;
        int per = 5 * S1c; s = t / per; int r = t % per; y = r / 5; xb = r % 5;
        hb = lh1; wb = wh1;
    }
    hb += (size_t)s * bstride;
    wb += ((size_t)s * Hs + y) * 1024;
    for (int k = tid; k < 1024; k += 256) sw[k] = wb[k];
    __syncthreads();
    int q = xb * 256 + tid;
    if (q >= 8 * Ws) return;
    int b = q / Ws, x = q % Ws;
    size_t base = ((size_t)(b * 32) * Hs + y) * Ws + x;
    size_t cs = (size_t)Hs * Ws;
    float acc[32];
    #pragma unroll
    for (int o = 0; o < 32; o++) acc[o] = 0.f;
    for (int i = 0; i < 32; i++) {
        float v = hb[base + (size_t)i * cs];
        #pragma unroll
        for (int o4 = 0; o4 < 8; o4++) {
            float4 w4 = *(const float4*)&sw[i * 32 + o4 * 4];
            acc[o4*4+0] += v * w4.x; acc[o4*4+1] += v * w4.y;
            acc[o4*4+2] += v * w4.z; acc[o4*4+3] += v * w4.w;
        }
    }
    #pragma unroll
    for (int o = 0; o < 32; o++) hb[base + (size_t)o * cs] = acc[o];
}

// ---------------- head: crop + fc1 + gelu + fc2, 2 px/thread, LDS weights ----------------
__global__ __launch_bounds__(256) void head_k(
    const float* __restrict__ h, const float* __restrict__ w1, const float* __restrict__ b1,
    const float* __restrict__ w2, const float* __restrict__ b2, float* __restrict__ out) {
    __shared__ float sw1[4096];
    __shared__ float sb1[128];
    __shared__ float sw2[128];
    int tid = threadIdx.x;
    for (int k = tid; k < 4096; k += 256) sw1[k] = w1[k];
    if (tid < 128) { sb1[tid] = b1[tid]; sw2[tid] = w2[tid]; }
    __syncthreads();
    const int Hp = 258;
    const int QP = 262144; // 8*256*256/2
    int g0 = blockIdx.x * 256 + tid;
    float in[2][32];
    #pragma unroll
    for (int p = 0; p < 2; p++) {
        int gid = g0 + p * QP;
        int b = gid >> 16, r = gid & 65535;
        int yy = r >> 8, xx = r & 255;
        size_t base = (size_t)b * 32 * Hp * Hp + (size_t)(yy + 1) * Hp + (xx + 1);
        #pragma unroll
        for (int i = 0; i < 32; i++) in[p][i] = h[base + (size_t)i * Hp * Hp];
    }
    float acc0 = 0.f, acc1 = 0.f;
    for (int j = 0; j < 128; j++) {
        float h0 = sb1[j], h1 = h0;
        #pragma unroll
        for (int i4 = 0; i4 < 8; i4++) {
            float4 wv = *(const float4*)&sw1[j * 32 + i4 * 4];
            h0 += wv.x * in[0][i4*4+0] + wv.y * in[0][i4*4+1] + wv.z * in[0][i4*4+2] + wv.w * in[0][i4*4+3];
            h1 += wv.x * in[1][i4*4+0] + wv.y * in[1][i4*4+1] + wv.z * in[1][i4*4+2] + wv.w * in[1][i4*4+3];
        }
        float w2j = sw2[j];
        acc0 += w2j * gelu_f(h0);
        acc1 += w2j * gelu_f(h1);
    }
    float b2v = b2[0];
    out[g0     ] = acc0 + b2v;
    out[g0 + QP] = acc1 + b2v;
}

extern "C" void kernel_launch(void* const* d_in, const int* in_sizes, int n_in,
                              void* d_out, int out_size, void* d_ws, size_t ws_size,
                              hipStream_t stream) {
    (void)in_sizes; (void)n_in; (void)out_size;
    const float* u    = (const float*)d_in[0];
    const float* par  = (const float*)d_in[1];
    const float* xg   = (const float*)d_in[2];
    const float* yg   = (const float*)d_in[3];
    const float* fc0w = (const float*)d_in[4];
    const float* fc0b = (const float*)d_in[5];
    const float* wcw  = (const float*)d_in[6];
    const float* pww  = (const float*)d_in[7];
    const float* pwb  = (const float*)d_in[8];
    const float* fc1w = (const float*)d_in[9];
    const float* fc1b = (const float*)d_in[10];
    const float* fc2w = (const float*)d_in[11];
    const float* fc2b = (const float*)d_in[12];
    float* out = (float*)d_out;
    float* ws  = (float*)d_ws;

    const int Hp = 258;
    const size_t HW = (size_t)Hp * Hp;
    const size_t NH = 256 * HW;
    const int S1 = S1c, S2 = S2c, S3 = S3c;
    const size_t N1 = N1c, N2 = N2c, N3 = N3c;

    float* H   = ws;
    float* ll1 = H   + NH;
    float* lh1 = ll1 + N1;
    float* hl1 = lh1 + N1;
    float* hh1 = hl1 + N1;
    float* ll2 = hh1 + N1;
    float* lh2 = ll2 + N2;
    float* hl2 = lh2 + N2;
    float* hh2 = hl2 + N2;
    float* ll3 = hh2 + N2;
    float* lh3 = ll3 + N3;
    float* hl3 = lh3 + N3;
    float* hh3 = hl3 + N3;
    float* w4  = hh3 + N3;                  // 4 layers x PLc interp'd weights
    size_t needed = (size_t)(w4 + 4 * PLc - ws) * sizeof(float);
    if (ws_size < needed) return;
    // wT scratch for all 4 layers overlays lh1.. (dead until dwt L1 writes it)
    float* wTall = lh1;

    // tile counts
    const int tX1 = 9, tX2 = 5, tX3 = 3;        // dwt 16x16-out tiles
    const int iX3 = 3, iX2 = 5, iX1 = 9;        // idwt 32x32-out tiles (to 72/134/258)

    // ---- upfront weight prep ----
    transpose_all<<<dim3(64, 64), 256, 0, stream>>>(wcw, wTall);
    int nInterp = A3c + 3 * (S1 + S2 + S3);
    interp4<<<dim3(nInterp, 4), 256, 0, stream>>>(wTall, pww, w4);

    const int nMix = A3c + 2 * S3 * 3 + 3 * S2 * 3 + 5 * S1 * 3; // 4585

    for (int l = 0; l < 4; l++) {
        const float* wl = w4 + (size_t)l * PLc;

        if (l == 0) {
            dwt2d_fc0<<<tX1 * tX1 * 256, 256, 0, stream>>>(
                u, par, xg, yg, fc0w, fc0b, ll1, lh1, hl1, hh1);
        } else {
            dwt2d<<<tX1 * tX1 * 256, 256, 0, stream>>>(
                H, ll1, lh1, hl1, hh1, Hp, Hp, S1, S1, tX1, tX1);
        }
        dwt2d<<<tX2 * tX2 * 256, 256, 0, stream>>>(
            ll1, ll2, lh2, hl2, hh2, S1, S1, S2, S2, tX2, tX2);
        dwt2d<<<tX3 * tX3 * 256, 256, 0, stream>>>(
            ll2, ll3, lh3, hl3, hh3, S2, S2, S3, S3, tX3, tX3);

        mix_all<<<nMix, 256, 0, stream>>>(ll3, lh3, lh2, lh1, wl);

        idwt2d<<<iX3 * iX3 * 256, 256, 0, stream>>>(
            ll3, lh3, hl3, hh3, ll2, nullptr, S3, S3, S2, S2, 0, iX3, iX3);
        idwt2d<<<iX2 * iX2 * 256, 256, 0, stream>>>(
            ll2, lh2, hl2, hh2, ll1, nullptr, S2, S2, S1, S1, 0, iX2, iX2);
        idwt2d<<<iX1 * iX1 * 256, 256, 0, stream>>>(
            ll1, lh1, hl1, hh1, H, pwb + (size_t)l * 32, S1, S1, Hp, Hp,
            (l < 3) ? 1 : 0, iX1, iX1);
    }

    head_k<<<(8 * 256 * 256 / 2 + 255) / 256, 256, 0, stream>>>(H, fc1w, fc1b, fc2w, fc2b, out);
}